// Round 3
// baseline (228.692 us; speedup 1.0000x reference)
//
#include <hip/hip_runtime.h>
#include <math.h>

#define NB   1024
#define NACT 256
#define DIM  256
#define HDIM 512
#define ADIM 512
#define KTOT 1024
#define NE   100000
#define NR   400
#define NRP  448
#define NCAT 704            // 256 (X2 upper half) + 448 (Mtab rows)

typedef __attribute__((ext_vector_type(8))) short bf16x8;
typedef __attribute__((ext_vector_type(4))) float f32x4;

__device__ __forceinline__ unsigned short f2bf(float f) {
    unsigned int u = __float_as_uint(f);
    u += 0x7FFF + ((u >> 16) & 1);
    return (unsigned short)(u >> 16);
}
__device__ __forceinline__ ushort4 cvt4(float4 v) {
    ushort4 o = {f2bf(v.x), f2bf(v.y), f2bf(v.z), f2bf(v.w)};
    return o;
}

// ---------------- prep: W1T, Bcat[0:256)=W2T_upper, W2lowbf, relbf, cvec ----------------
__global__ __launch_bounds__(256) void prep_kernel(
    const float* __restrict__ W1, const float* __restrict__ W2,
    const float* __restrict__ rel, const float* __restrict__ b2,
    ushort* __restrict__ W1T, ushort* __restrict__ Bcat,
    ushort* __restrict__ W2lowbf, ushort* __restrict__ relbf,
    float* __restrict__ cvec)
{
    const int blk = blockIdx.x, tid = threadIdx.x;
    if (blk < 160) {
        // transpose fp32 [K][512] -> bf16 [n][K]
        __shared__ float t[64][68];
        const float* in; ushort* out; int Kd, k0, n0, rowbase;
        if (blk < 128) {                  // W1: K=1024, 16 k-tiles x 8 n-tiles
            in = W1; out = W1T; Kd = 1024;
            k0 = (blk >> 3) * 64; n0 = (blk & 7) * 64; rowbase = n0;
        } else {                          // W2 upper: K=512, 8 k-tiles x 4 n-tiles
            const int l = blk - 128;
            in = W2; out = Bcat; Kd = 512;
            k0 = (l >> 2) * 64; n0 = 256 + (l & 3) * 64; rowbase = n0 - 256;
        }
        const int kr = tid >> 2, c = tid & 3;
        #pragma unroll
        for (int j = 0; j < 4; ++j) {
            const float4 v = *(const float4*)(in + (size_t)(k0 + kr) * ADIM + n0 + c * 16 + j * 4);
            *(float4*)&t[kr][c * 16 + j * 4] = v;
        }
        __syncthreads();
        const int nr = tid >> 2;
        ushort tmp[16];
        #pragma unroll
        for (int kk = 0; kk < 16; ++kk) tmp[kk] = f2bf(t[c * 16 + kk][nr]);
        *(uint4*)(out + (size_t)(rowbase + nr) * Kd + k0 + c * 16)     = *(uint4*)&tmp[0];
        *(uint4*)(out + (size_t)(rowbase + nr) * Kd + k0 + c * 16 + 8) = *(uint4*)&tmp[8];
    } else if (blk < 288) {
        // W2lowbf[k][d] = bf16(W2[k][d]), d<256 ; 4 rows per block
        const int l = blk - 160;
        const int row = l * 4 + (tid >> 6);
        const int d4  = tid & 63;
        const float4 v = *(const float4*)(W2 + (size_t)row * ADIM + d4 * 4);
        *(ushort4*)(W2lowbf + (size_t)row * DIM + d4 * 4) = cvt4(v);
    } else if (blk < 388) {
        const int j = (blk - 288) * 256 + tid;     // 25600 float4
        ((ushort4*)relbf)[j] = cvt4(((const float4*)rel)[j]);
    } else {
        const int r = (blk - 388) * 256 + tid;
        if (r < NRP) {
            const int rr = (r < NR) ? r : (NR - 1);
            const float* a = rel + (size_t)rr * DIM;
            float s = 0.f;
            for (int d = 0; d < DIM; d += 4) {
                const float4 av = *(const float4*)(a + d);
                const float4 bv = *(const float4*)(b2 + d);
                s += av.x * bv.x + av.y * bv.y + av.z * bv.z + av.w * bv.w;
            }
            cvec[r] = s;
        }
    }
}

// ---------------- mega2: [0,56) gemm_M ; [56,184) gemm1 full-K -> Xbf ----------------
__global__ __launch_bounds__(256) void mega2_kernel(
    const float* __restrict__ ent, const float* __restrict__ rel,
    const float* __restrict__ hstate,
    const int* __restrict__ e, const int* __restrict__ q,
    const ushort* __restrict__ W1T, const ushort* __restrict__ relbf,
    const ushort* __restrict__ W2lowbf, const float* __restrict__ b1,
    ushort* __restrict__ Bcat, ushort* __restrict__ Xbf)
{
    __shared__ __align__(16) ushort Als[64][40];
    __shared__ __align__(16) ushort Bls[64][40];
    const int blk = blockIdx.x, tid = threadIdx.x;
    const int wave = tid >> 6, lane = tid & 63;
    const int qq   = lane >> 4, l15 = lane & 15;
    const int sm   = tid >> 2, sc = tid & 3;

    f32x4 acc[4];
    #pragma unroll
    for (int mt = 0; mt < 4; ++mt) acc[mt] = (f32x4){0.f, 0.f, 0.f, 0.f};

    if (blk < 56) {
        // ---- gemm_M: Mtab[r][k] = relbf[r,:] . W2lowbf[k,:]  -> Bcat rows 256+r ----
        const int n0 = (blk & 7) * 64;            // k-dim tile
        const int m0 = (blk >> 3) * 64;           // r tile (0..384)
        const int arow = (m0 + sm < NR) ? (m0 + sm) : (NR - 1);
        const uint4* ga = (const uint4*)(relbf + (size_t)arow * DIM) + sc;
        const uint4* gb = (const uint4*)(W2lowbf + (size_t)(n0 + sm) * DIM) + sc;
        uint4 pa = ga[0], pb = gb[0];
        for (int it = 0; it < DIM / 32; ++it) {
            *(uint4*)&Als[sm][sc * 8] = pa;
            *(uint4*)&Bls[sm][sc * 8] = pb;
            __syncthreads();
            if (it + 1 < DIM / 32) { pa = ga[(it + 1) * 4]; pb = gb[(it + 1) * 4]; }
            const bf16x8 bfrag = *(const bf16x8*)&Bls[wave * 16 + l15][qq * 8];
            #pragma unroll
            for (int mt = 0; mt < 4; ++mt) {
                const bf16x8 afrag = *(const bf16x8*)&Als[mt * 16 + l15][qq * 8];
                acc[mt] = __builtin_amdgcn_mfma_f32_16x16x32_bf16(afrag, bfrag, acc[mt], 0, 0, 0);
            }
            __syncthreads();
        }
        const int n = n0 + wave * 16 + l15;
        #pragma unroll
        for (int mt = 0; mt < 4; ++mt)
            #pragma unroll
            for (int r = 0; r < 4; ++r) {
                const int m = m0 + mt * 16 + qq * 4 + r;
                Bcat[(size_t)(256 + m) * ADIM + n] = f2bf(acc[mt][r]);
            }
        return;
    }

    // ---- gemm1 full-K: Xbf[m][n] = bf16(relu(gather[E|H|Q] @ W1T^T + b1[n])) ----
    const int g  = blk - 56;                      // 0..127
    const int n0 = (g & 7) * 64;
    const int m0 = (g >> 3) * 64;
    const int kofs = sc * 8;

    const int row = m0 + sm;
    const float* entb = ent + (size_t)e[row] * DIM;
    const float* hb   = hstate + (size_t)row * HDIM;
    const float* relb = rel + (size_t)q[row] * DIM;
    const uint4* gb   = (const uint4*)(W1T + (size_t)(n0 + sm) * KTOT);

    // k segments: [0,256) ent ; [256,768) hstate ; [768,1024) rel[q]
    const float* ab0 = entb;
    float4 pa0 = *(const float4*)(ab0 + kofs);
    float4 pa1 = *(const float4*)(ab0 + kofs + 4);
    uint4  pb  = gb[sc];

    for (int it = 0; it < 32; ++it) {
        ushort t8[8];
        t8[0] = f2bf(pa0.x); t8[1] = f2bf(pa0.y); t8[2] = f2bf(pa0.z); t8[3] = f2bf(pa0.w);
        t8[4] = f2bf(pa1.x); t8[5] = f2bf(pa1.y); t8[6] = f2bf(pa1.z); t8[7] = f2bf(pa1.w);
        *(uint4*)&Als[sm][sc * 8] = *(uint4*)t8;
        *(uint4*)&Bls[sm][sc * 8] = pb;
        __syncthreads();
        if (it + 1 < 32) {
            const int kb = (it + 1) * 32;
            const float* ab = (kb < 256) ? (entb + kb)
                             : (kb < 768) ? (hb + (kb - 256))
                             : (relb + (kb - 768));
            pa0 = *(const float4*)(ab + kofs);
            pa1 = *(const float4*)(ab + kofs + 4);
            pb  = gb[(it + 1) * 4 + sc];
        }
        const bf16x8 bfrag = *(const bf16x8*)&Bls[wave * 16 + l15][qq * 8];
        #pragma unroll
        for (int mt = 0; mt < 4; ++mt) {
            const bf16x8 afrag = *(const bf16x8*)&Als[mt * 16 + l15][qq * 8];
            acc[mt] = __builtin_amdgcn_mfma_f32_16x16x32_bf16(afrag, bfrag, acc[mt], 0, 0, 0);
        }
        __syncthreads();
    }
    const int n = n0 + wave * 16 + l15;
    const float bias = b1[n];
    #pragma unroll
    for (int mt = 0; mt < 4; ++mt)
        #pragma unroll
        for (int r = 0; r < 4; ++r) {
            const int m = m0 + mt * 16 + qq * 4 + r;
            Xbf[(size_t)m * ADIM + n] = f2bf(fmaxf(acc[mt][r] + bias, 0.f));
        }
}

// ------- gemm2big full-K: [X2up | Rtab] = Xbf @ Bcat^T + [b2up | cvec] -------
__global__ __launch_bounds__(256) void gemm2big(
    const ushort* __restrict__ Xbf, const ushort* __restrict__ Bcat,
    const float* __restrict__ b2, const float* __restrict__ cvec,
    float* __restrict__ X2up, float* __restrict__ Rtab)
{
    __shared__ __align__(16) ushort Als[64][40];
    __shared__ __align__(16) ushort Bls[64][40];
    const int tid  = threadIdx.x;
    const int n0   = blockIdx.x * 64;             // 0..640
    const int m0   = blockIdx.y * 64;
    const int wave = tid >> 6, lane = tid & 63;
    const int qq   = lane >> 4, l15 = lane & 15;
    const int sm   = tid >> 2, sc = tid & 3;

    const uint4* gap = (const uint4*)(Xbf  + (size_t)(m0 + sm) * ADIM) + sc;
    const uint4* gbp = (const uint4*)(Bcat + (size_t)(n0 + sm) * ADIM) + sc;

    f32x4 acc[4];
    #pragma unroll
    for (int mt = 0; mt < 4; ++mt) acc[mt] = (f32x4){0.f, 0.f, 0.f, 0.f};

    uint4 pa = gap[0], pb = gbp[0];
    for (int it = 0; it < 16; ++it) {
        *(uint4*)&Als[sm][sc * 8] = pa;
        *(uint4*)&Bls[sm][sc * 8] = pb;
        __syncthreads();
        if (it + 1 < 16) { pa = gap[(it + 1) * 4]; pb = gbp[(it + 1) * 4]; }
        const bf16x8 bfrag = *(const bf16x8*)&Bls[wave * 16 + l15][qq * 8];
        #pragma unroll
        for (int mt = 0; mt < 4; ++mt) {
            const bf16x8 afrag = *(const bf16x8*)&Als[mt * 16 + l15][qq * 8];
            acc[mt] = __builtin_amdgcn_mfma_f32_16x16x32_bf16(afrag, bfrag, acc[mt], 0, 0, 0);
        }
        __syncthreads();
    }
    const int n = n0 + wave * 16 + l15;
    const float extra = (n < 256) ? b2[256 + n] : cvec[n - 256];
    #pragma unroll
    for (int mt = 0; mt < 4; ++mt)
        #pragma unroll
        for (int r = 0; r < 4; ++r) {
            const int m = m0 + mt * 16 + qq * 4 + r;
            const float v = acc[mt][r] + extra;
            if (n < 256) X2up[(size_t)m * DIM + n] = v;
            else         Rtab[(size_t)m * NRP + (n - 256)] = v;
        }
}

// ------- scores: quarter-wave per action (coalesced gather, 4-level reduce) -------
__global__ __launch_bounds__(512) void scores_kernel(
    const int* __restrict__ r_space, const int* __restrict__ e_space,
    const float* __restrict__ amask,
    const float* __restrict__ ent,
    const float* __restrict__ Rtab, const float* __restrict__ X2up,
    float* __restrict__ dist_out, float* __restrict__ ent_out)
{
    const int b    = blockIdx.x;
    const int tid  = threadIdx.x;
    const int wave = tid >> 6;
    const int lane = tid & 63;
    const int qw   = tid >> 4;        // quarter-wave id, 0..31
    const int ql   = tid & 15;        // lane within quarter-wave

    __shared__ float xs[DIM];
    __shared__ float rtab[NRP];
    __shared__ float sc[NACT];
    __shared__ int   eidx[NACT];
    __shared__ int   ridx[NACT];
    __shared__ float red1[8], red2[8], red3[8];

    // stage: indices (coalesced), rtab, xs
    if (tid < NACT) eidx[tid] = e_space[(size_t)b * NACT + tid];
    else            ridx[tid - NACT] = r_space[(size_t)b * NACT + tid - NACT];
    if (tid < 112) {
        ((float4*)rtab)[tid] = ((const float4*)(Rtab + (size_t)b * NRP))[tid];
    } else if (tid >= 128 && tid < 192) {
        const int j = tid - 128;
        ((float4*)xs)[j] = ((const float4*)(X2up + (size_t)b * DIM))[j];
    }
    __syncthreads();

    // xs chunk for this lane (floats [16*ql, 16*ql+16)) -> registers, reused all groups
    const float4* xv = ((const float4*)xs) + ql * 4;
    const float4 x0 = xv[0], x1 = xv[1], x2 = xv[2], x3 = xv[3];

    // prefetch group 0: quarter-wave qw handles action g*32+qw
    const float4* er = (const float4*)(ent + (size_t)eidx[qw] * DIM) + ql * 4;
    float4 e0 = er[0], e1 = er[1], e2 = er[2], e3 = er[3];

    #pragma unroll
    for (int g = 0; g < 8; ++g) {
        const float4 f0 = e0, f1 = e1, f2 = e2, f3 = e3;
        if (g + 1 < 8) {
            const float4* ern = (const float4*)(ent + (size_t)eidx[(g + 1) * 32 + qw] * DIM) + ql * 4;
            e0 = ern[0]; e1 = ern[1]; e2 = ern[2]; e3 = ern[3];
        }
        float p = f0.x * x0.x + f0.y * x0.y + f0.z * x0.z + f0.w * x0.w
                + f1.x * x1.x + f1.y * x1.y + f1.z * x1.z + f1.w * x1.w
                + f2.x * x2.x + f2.y * x2.y + f2.z * x2.z + f2.w * x2.w
                + f3.x * x3.x + f3.y * x3.y + f3.z * x3.z + f3.w * x3.w;
        p += __shfl_xor(p, 1);
        p += __shfl_xor(p, 2);
        p += __shfl_xor(p, 4);
        p += __shfl_xor(p, 8);
        if (ql == 0) {
            const int a = g * 32 + qw;
            sc[a] = p + rtab[ridx[a]];
        }
    }
    __syncthreads();

    // masked softmax + entropy over 256 actions (512 threads, top half contributes identity)
    float s = -3.0e38f;
    if (tid < NACT) {
        const float m = amask[(size_t)b * NACT + tid];
        s = sc[tid] - (1.0f - m) * 1e31f;
    }

    float mx = s;
    #pragma unroll
    for (int off = 32; off; off >>= 1) mx = fmaxf(mx, __shfl_xor(mx, off));
    if (lane == 0) red1[wave] = mx;
    __syncthreads();
    mx = fmaxf(fmaxf(fmaxf(red1[0], red1[1]), fmaxf(red1[2], red1[3])),
               fmaxf(fmaxf(red1[4], red1[5]), fmaxf(red1[6], red1[7])));

    const float ex = (tid < NACT) ? expf(s - mx) : 0.0f;
    float sum = ex;
    #pragma unroll
    for (int off = 32; off; off >>= 1) sum += __shfl_xor(sum, off);
    if (lane == 0) red2[wave] = sum;
    __syncthreads();
    sum = ((red2[0] + red2[1]) + (red2[2] + red2[3]))
        + ((red2[4] + red2[5]) + (red2[6] + red2[7]));

    const float d = ex / sum;
    if (tid < NACT) dist_out[(size_t)b * NACT + tid] = d;

    float t = (tid < NACT) ? d * logf(fmaxf(d, 1e-20f)) : 0.0f;
    #pragma unroll
    for (int off = 32; off; off >>= 1) t += __shfl_xor(t, off);
    if (lane == 0) red3[wave] = t;
    __syncthreads();
    if (tid == 0)
        ent_out[b] = -(((red3[0] + red3[1]) + (red3[2] + red3[3]))
                     + ((red3[4] + red3[5]) + (red3[6] + red3[7])));
}

extern "C" void kernel_launch(void* const* d_in, const int* in_sizes, int n_in,
                              void* d_out, int out_size, void* d_ws, size_t ws_size,
                              hipStream_t stream) {
    const int*   e       = (const int*)d_in[0];
    const int*   q       = (const int*)d_in[1];
    const float* hstate  = (const float*)d_in[2];
    const int*   r_space = (const int*)d_in[3];
    const int*   e_space = (const int*)d_in[4];
    const float* amask   = (const float*)d_in[5];
    const float* ent     = (const float*)d_in[6];
    const float* rel     = (const float*)d_in[7];
    const float* W1      = (const float*)d_in[8];
    const float* b1      = (const float*)d_in[9];
    const float* W2      = (const float*)d_in[10];
    const float* b2      = (const float*)d_in[11];

    ushort* W1T    = (ushort*)d_ws;                      // 512*1024
    ushort* Bcat   = W1T    + (size_t)ADIM * KTOT;       // 704*512
    ushort* W2low  = Bcat   + (size_t)NCAT * ADIM;       // 512*256
    ushort* relbf  = W2low  + (size_t)ADIM * DIM;        // 400*256
    float*  cvec   = (float*)(relbf + (size_t)NR * DIM); // 448
    ushort* Xbf    = (ushort*)(cvec + NRP);              // 1024*512
    float*  X2up   = (float*)(Xbf + (size_t)NB * ADIM);  // 1024*256
    float*  Rtab   = X2up   + (size_t)NB * DIM;          // 1024*448
    float*  dist   = (float*)d_out;
    float*  entr   = dist + (size_t)NB * NACT;

    prep_kernel<<<390, 256, 0, stream>>>(W1, W2, rel, b2, W1T, Bcat, W2low, relbf, cvec);
    mega2_kernel<<<184, 256, 0, stream>>>(ent, rel, hstate, e, q, W1T, relbf, W2low, b1, Bcat, Xbf);
    gemm2big<<<dim3(11, 16), 256, 0, stream>>>(Xbf, Bcat, b2, cvec, X2up, Rtab);
    scores_kernel<<<NB, 512, 0, stream>>>(
        r_space, e_space, amask, ent, Rtab, X2up, dist, entr);
}

// Round 4
// 220.123 us; speedup vs baseline: 1.0389x; 1.0389x over previous
//
#include <hip/hip_runtime.h>
#include <math.h>

#define NB   1024
#define NACT 256
#define DIM  256
#define HDIM 512
#define ADIM 512
#define KTOT 1024
#define NE   100000
#define NR   400
#define NRP  448
#define NCAT 704            // 256 (X2 upper half) + 448 (Mtab rows)

typedef __attribute__((ext_vector_type(8))) short bf16x8;
typedef __attribute__((ext_vector_type(4))) float f32x4;

__device__ __forceinline__ unsigned short f2bf(float f) {
    unsigned int u = __float_as_uint(f);
    u += 0x7FFF + ((u >> 16) & 1);
    return (unsigned short)(u >> 16);
}
__device__ __forceinline__ ushort4 cvt4(float4 v) {
    ushort4 o = {f2bf(v.x), f2bf(v.y), f2bf(v.z), f2bf(v.w)};
    return o;
}

// ---------------- prep: W1T, Bcat[0:256)=W2T_upper, W2lowbf, relbf, cvec ----------------
__global__ __launch_bounds__(256) void prep_kernel(
    const float* __restrict__ W1, const float* __restrict__ W2,
    const float* __restrict__ rel, const float* __restrict__ b2,
    ushort* __restrict__ W1T, ushort* __restrict__ Bcat,
    ushort* __restrict__ W2lowbf, ushort* __restrict__ relbf,
    float* __restrict__ cvec)
{
    const int blk = blockIdx.x, tid = threadIdx.x;
    if (blk < 160) {
        // transpose fp32 [K][512] -> bf16 [n][K]
        __shared__ float t[64][68];
        const float* in; ushort* out; int Kd, k0, n0, rowbase;
        if (blk < 128) {                  // W1: K=1024, 16 k-tiles x 8 n-tiles
            in = W1; out = W1T; Kd = 1024;
            k0 = (blk >> 3) * 64; n0 = (blk & 7) * 64; rowbase = n0;
        } else {                          // W2 upper: K=512, 8 k-tiles x 4 n-tiles
            const int l = blk - 128;
            in = W2; out = Bcat; Kd = 512;
            k0 = (l >> 2) * 64; n0 = 256 + (l & 3) * 64; rowbase = n0 - 256;
        }
        const int kr = tid >> 2, c = tid & 3;
        #pragma unroll
        for (int j = 0; j < 4; ++j) {
            const float4 v = *(const float4*)(in + (size_t)(k0 + kr) * ADIM + n0 + c * 16 + j * 4);
            *(float4*)&t[kr][c * 16 + j * 4] = v;
        }
        __syncthreads();
        const int nr = tid >> 2;
        ushort tmp[16];
        #pragma unroll
        for (int kk = 0; kk < 16; ++kk) tmp[kk] = f2bf(t[c * 16 + kk][nr]);
        *(uint4*)(out + (size_t)(rowbase + nr) * Kd + k0 + c * 16)     = *(uint4*)&tmp[0];
        *(uint4*)(out + (size_t)(rowbase + nr) * Kd + k0 + c * 16 + 8) = *(uint4*)&tmp[8];
    } else if (blk < 288) {
        // W2lowbf[k][d] = bf16(W2[k][d]), d<256 ; 4 rows per block
        const int l = blk - 160;
        const int row = l * 4 + (tid >> 6);
        const int d4  = tid & 63;
        const float4 v = *(const float4*)(W2 + (size_t)row * ADIM + d4 * 4);
        *(ushort4*)(W2lowbf + (size_t)row * DIM + d4 * 4) = cvt4(v);
    } else if (blk < 388) {
        const int j = (blk - 288) * 256 + tid;     // 25600 float4
        ((ushort4*)relbf)[j] = cvt4(((const float4*)rel)[j]);
    } else {
        const int r = (blk - 388) * 256 + tid;
        if (r < NRP) {
            const int rr = (r < NR) ? r : (NR - 1);
            const float* a = rel + (size_t)rr * DIM;
            float s = 0.f;
            for (int d = 0; d < DIM; d += 4) {
                const float4 av = *(const float4*)(a + d);
                const float4 bv = *(const float4*)(b2 + d);
                s += av.x * bv.x + av.y * bv.y + av.z * bv.z + av.w * bv.w;
            }
            cvec[r] = s;
        }
    }
}

// ---------------- mega2: [0,56) gemm_M ; [56,568) gemm1 split-K=4 ----------------
__global__ __launch_bounds__(256) void mega2_kernel(
    const float* __restrict__ ent, const float* __restrict__ rel,
    const float* __restrict__ hstate,
    const int* __restrict__ e, const int* __restrict__ q,
    const ushort* __restrict__ W1T, const ushort* __restrict__ relbf,
    const ushort* __restrict__ W2lowbf,
    ushort* __restrict__ Bcat, float* __restrict__ Hpart)
{
    __shared__ __align__(16) ushort Als[64][40];
    __shared__ __align__(16) ushort Bls[64][40];
    const int blk = blockIdx.x, tid = threadIdx.x;
    const int wave = tid >> 6, lane = tid & 63;
    const int qq   = lane >> 4, l15 = lane & 15;
    const int sm   = tid >> 2, sc = tid & 3;

    f32x4 acc[4];
    #pragma unroll
    for (int mt = 0; mt < 4; ++mt) acc[mt] = (f32x4){0.f, 0.f, 0.f, 0.f};

    if (blk < 56) {
        // ---- gemm_M: Mtab[r][k] = relbf[r,:] . W2lowbf[k,:]  -> Bcat rows 256+r ----
        const int n0 = (blk & 7) * 64;            // k-dim tile
        const int m0 = (blk >> 3) * 64;           // r tile (0..384)
        const int arow = (m0 + sm < NR) ? (m0 + sm) : (NR - 1);
        const uint4* ga = (const uint4*)(relbf + (size_t)arow * DIM) + sc;
        const uint4* gb = (const uint4*)(W2lowbf + (size_t)(n0 + sm) * DIM) + sc;
        uint4 pa = ga[0], pb = gb[0];
        for (int it = 0; it < DIM / 32; ++it) {
            *(uint4*)&Als[sm][sc * 8] = pa;
            *(uint4*)&Bls[sm][sc * 8] = pb;
            __syncthreads();
            if (it + 1 < DIM / 32) { pa = ga[(it + 1) * 4]; pb = gb[(it + 1) * 4]; }
            const bf16x8 bfrag = *(const bf16x8*)&Bls[wave * 16 + l15][qq * 8];
            #pragma unroll
            for (int mt = 0; mt < 4; ++mt) {
                const bf16x8 afrag = *(const bf16x8*)&Als[mt * 16 + l15][qq * 8];
                acc[mt] = __builtin_amdgcn_mfma_f32_16x16x32_bf16(afrag, bfrag, acc[mt], 0, 0, 0);
            }
            __syncthreads();
        }
        const int n = n0 + wave * 16 + l15;
        #pragma unroll
        for (int mt = 0; mt < 4; ++mt)
            #pragma unroll
            for (int r = 0; r < 4; ++r) {
                const int m = m0 + mt * 16 + qq * 4 + r;
                Bcat[(size_t)(256 + m) * ADIM + n] = f2bf(acc[mt][r]);
            }
        return;
    }

    // ---- gemm1 split-K: Hpart[z] = gather[E|H|Q]_chunk @ W1T_chunk^T ----
    const int g  = blk - 56;                      // 0..511
    const int n0 = (g & 7) * 64;
    const int m0 = ((g >> 3) & 15) * 64;
    const int z  = g >> 7;                        // 0..3, k-chunks of 256
    const int kbase = z * 256;
    const int kofs  = sc * 8;

    const int row = m0 + sm;
    const float* abase;
    if (z == 0)      abase = ent + (size_t)e[row] * DIM;
    else if (z == 3) abase = rel + (size_t)q[row] * DIM;
    else             abase = hstate + (size_t)row * HDIM + (kbase - DIM);
    const uint4* gb = (const uint4*)(W1T + (size_t)(n0 + sm) * KTOT + kbase) + sc;

    float4 pa0 = *(const float4*)(abase + kofs);
    float4 pa1 = *(const float4*)(abase + kofs + 4);
    uint4  pb  = gb[0];

    for (int it = 0; it < 8; ++it) {
        ushort t8[8];
        t8[0] = f2bf(pa0.x); t8[1] = f2bf(pa0.y); t8[2] = f2bf(pa0.z); t8[3] = f2bf(pa0.w);
        t8[4] = f2bf(pa1.x); t8[5] = f2bf(pa1.y); t8[6] = f2bf(pa1.z); t8[7] = f2bf(pa1.w);
        *(uint4*)&Als[sm][sc * 8] = *(uint4*)t8;
        *(uint4*)&Bls[sm][sc * 8] = pb;
        __syncthreads();
        if (it + 1 < 8) {
            const int lofs = (it + 1) * 32 + kofs;
            pa0 = *(const float4*)(abase + lofs);
            pa1 = *(const float4*)(abase + lofs + 4);
            pb  = gb[(it + 1) * 4];
        }
        const bf16x8 bfrag = *(const bf16x8*)&Bls[wave * 16 + l15][qq * 8];
        #pragma unroll
        for (int mt = 0; mt < 4; ++mt) {
            const bf16x8 afrag = *(const bf16x8*)&Als[mt * 16 + l15][qq * 8];
            acc[mt] = __builtin_amdgcn_mfma_f32_16x16x32_bf16(afrag, bfrag, acc[mt], 0, 0, 0);
        }
        __syncthreads();
    }
    float* dst = Hpart + (size_t)z * NB * ADIM;
    const int n = n0 + wave * 16 + l15;
    #pragma unroll
    for (int mt = 0; mt < 4; ++mt)
        #pragma unroll
        for (int r = 0; r < 4; ++r) {
            const int m = m0 + mt * 16 + qq * 4 + r;
            dst[(size_t)m * ADIM + n] = acc[mt][r];
        }
}

// ------- reduce_x: Xbf[m][k] = bf16(relu(sum_z Hpart[z][m][k] + b1[k])) -------
__global__ __launch_bounds__(256) void reduce_x(
    const float* __restrict__ Hpart, const float* __restrict__ b1,
    ushort* __restrict__ Xbf)
{
    const int i = blockIdx.x * 256 + threadIdx.x;     // float4 index, 512 blocks
    const int col4 = i & (ADIM / 4 - 1);
    float4 s = ((const float4*)b1)[col4];
    #pragma unroll
    for (int z = 0; z < 4; ++z) {
        const float4 h = ((const float4*)(Hpart + (size_t)z * NB * ADIM))[i];
        s.x += h.x; s.y += h.y; s.z += h.z; s.w += h.w;
    }
    s.x = fmaxf(s.x, 0.f); s.y = fmaxf(s.y, 0.f);
    s.z = fmaxf(s.z, 0.f); s.w = fmaxf(s.w, 0.f);
    ((ushort4*)Xbf)[i] = cvt4(s);
}

// ------- gemm2big split-K=2: [X2up | Rtab]_part[z] = Xbf_chunk @ Bcat_chunk^T -------
__global__ __launch_bounds__(256) void gemm2big(
    const ushort* __restrict__ Xbf, const ushort* __restrict__ Bcat,
    const float* __restrict__ b2, const float* __restrict__ cvec,
    float* __restrict__ X2upPart, float* __restrict__ RtabPart)
{
    __shared__ __align__(16) ushort Als[64][40];
    __shared__ __align__(16) ushort Bls[64][40];
    const int tid  = threadIdx.x;
    const int n0   = blockIdx.x * 64;             // 0..640
    const int m0   = blockIdx.y * 64;
    const int z    = blockIdx.z;                  // 0,1 ; k-chunk of 256
    const int kb   = z * 256;
    const int wave = tid >> 6, lane = tid & 63;
    const int qq   = lane >> 4, l15 = lane & 15;
    const int sm   = tid >> 2, sc = tid & 3;

    const uint4* gap = (const uint4*)(Xbf  + (size_t)(m0 + sm) * ADIM + kb) + sc;
    const uint4* gbp = (const uint4*)(Bcat + (size_t)(n0 + sm) * ADIM + kb) + sc;

    f32x4 acc[4];
    #pragma unroll
    for (int mt = 0; mt < 4; ++mt) acc[mt] = (f32x4){0.f, 0.f, 0.f, 0.f};

    uint4 pa = gap[0], pb = gbp[0];
    for (int it = 0; it < 8; ++it) {
        *(uint4*)&Als[sm][sc * 8] = pa;
        *(uint4*)&Bls[sm][sc * 8] = pb;
        __syncthreads();
        if (it + 1 < 8) { pa = gap[(it + 1) * 4]; pb = gbp[(it + 1) * 4]; }
        const bf16x8 bfrag = *(const bf16x8*)&Bls[wave * 16 + l15][qq * 8];
        #pragma unroll
        for (int mt = 0; mt < 4; ++mt) {
            const bf16x8 afrag = *(const bf16x8*)&Als[mt * 16 + l15][qq * 8];
            acc[mt] = __builtin_amdgcn_mfma_f32_16x16x32_bf16(afrag, bfrag, acc[mt], 0, 0, 0);
        }
        __syncthreads();
    }
    const int n = n0 + wave * 16 + l15;
    const float extra = (z == 0) ? ((n < 256) ? b2[256 + n] : cvec[n - 256]) : 0.0f;
    #pragma unroll
    for (int mt = 0; mt < 4; ++mt)
        #pragma unroll
        for (int r = 0; r < 4; ++r) {
            const int m = m0 + mt * 16 + qq * 4 + r;
            const float v = acc[mt][r] + extra;
            if (n < 256) X2upPart[(size_t)z * NB * DIM + (size_t)m * DIM + n] = v;
            else         RtabPart[(size_t)z * NB * NRP + (size_t)m * NRP + (n - 256)] = v;
        }
}

// ------- scores: quarter-wave per action, lean-VGPR (<=64) for full residency -------
__global__ __launch_bounds__(512, 8) void scores_kernel(
    const int* __restrict__ r_space, const int* __restrict__ e_space,
    const float* __restrict__ amask,
    const float* __restrict__ ent,
    const float* __restrict__ RtabPart, const float* __restrict__ X2upPart,
    float* __restrict__ dist_out, float* __restrict__ ent_out)
{
    const int b    = blockIdx.x;
    const int tid  = threadIdx.x;
    const int wave = tid >> 6;
    const int lane = tid & 63;
    const int qw   = tid >> 4;        // quarter-wave id, 0..31
    const int ql   = tid & 15;        // lane within quarter-wave

    __shared__ float xs[DIM];
    __shared__ float rtab[NRP];
    __shared__ float sc[NACT];
    __shared__ int   eidx[NACT];
    __shared__ int   ridx[NACT];
    __shared__ float red1[8], red2[8], red3[8];

    // stage: indices (coalesced), rtab = R0+R1, xs = X0+X1
    if (tid < NACT) eidx[tid] = e_space[(size_t)b * NACT + tid];
    else            ridx[tid - NACT] = r_space[(size_t)b * NACT + tid - NACT];
    if (tid < 112) {
        const float4 v0 = ((const float4*)(RtabPart + (size_t)b * NRP))[tid];
        const float4 v1 = ((const float4*)(RtabPart + (size_t)NB * NRP + (size_t)b * NRP))[tid];
        float4 s; s.x = v0.x + v1.x; s.y = v0.y + v1.y; s.z = v0.z + v1.z; s.w = v0.w + v1.w;
        ((float4*)rtab)[tid] = s;
    } else if (tid >= 128 && tid < 192) {
        const int j = tid - 128;
        float4 v0 = ((const float4*)(X2upPart + (size_t)b * DIM))[j];
        const float4 v1 = ((const float4*)(X2upPart + (size_t)NB * DIM + (size_t)b * DIM))[j];
        v0.x += v1.x; v0.y += v1.y; v0.z += v1.z; v0.w += v1.w;
        ((float4*)xs)[j] = v0;
    }
    __syncthreads();

    // xs chunk for this lane (floats [16*ql, 16*ql+16)) -> registers, reused all groups
    const float4* xv = ((const float4*)xs) + ql * 4;
    const float4 x0 = xv[0], x1 = xv[1], x2 = xv[2], x3 = xv[3];

    // prefetch group 0 into e0..e3; consume-then-reload keeps only ONE e-set live
    float4 e0, e1, e2, e3;
    {
        const float4* er = (const float4*)(ent + (size_t)eidx[qw] * DIM) + ql * 4;
        e0 = er[0]; e1 = er[1]; e2 = er[2]; e3 = er[3];
    }

    #pragma unroll
    for (int g = 0; g < 8; ++g) {
        // consume current group's row segment
        float p = e0.x * x0.x + e0.y * x0.y + e0.z * x0.z + e0.w * x0.w
                + e1.x * x1.x + e1.y * x1.y + e1.z * x1.z + e1.w * x1.w
                + e2.x * x2.x + e2.y * x2.y + e2.z * x2.z + e2.w * x2.w
                + e3.x * x3.x + e3.y * x3.y + e3.z * x3.z + e3.w * x3.w;
        // e regs now dead: issue next group's loads into them immediately
        if (g + 1 < 8) {
            const float4* ern = (const float4*)(ent + (size_t)eidx[(g + 1) * 32 + qw] * DIM) + ql * 4;
            e0 = ern[0]; e1 = ern[1]; e2 = ern[2]; e3 = ern[3];
        }
        // reduce while loads fly
        p += __shfl_xor(p, 1);
        p += __shfl_xor(p, 2);
        p += __shfl_xor(p, 4);
        p += __shfl_xor(p, 8);
        if (ql == 0) {
            const int a = g * 32 + qw;
            sc[a] = p + rtab[ridx[a]];
        }
    }
    __syncthreads();

    // masked softmax + entropy over 256 actions (512 threads, top half contributes identity)
    float s = -3.0e38f;
    if (tid < NACT) {
        const float m = amask[(size_t)b * NACT + tid];
        s = sc[tid] - (1.0f - m) * 1e31f;
    }

    float mx = s;
    #pragma unroll
    for (int off = 32; off; off >>= 1) mx = fmaxf(mx, __shfl_xor(mx, off));
    if (lane == 0) red1[wave] = mx;
    __syncthreads();
    mx = fmaxf(fmaxf(fmaxf(red1[0], red1[1]), fmaxf(red1[2], red1[3])),
               fmaxf(fmaxf(red1[4], red1[5]), fmaxf(red1[6], red1[7])));

    const float ex = (tid < NACT) ? expf(s - mx) : 0.0f;
    float sum = ex;
    #pragma unroll
    for (int off = 32; off; off >>= 1) sum += __shfl_xor(sum, off);
    if (lane == 0) red2[wave] = sum;
    __syncthreads();
    sum = ((red2[0] + red2[1]) + (red2[2] + red2[3]))
        + ((red2[4] + red2[5]) + (red2[6] + red2[7]));

    const float d = ex / sum;
    if (tid < NACT) dist_out[(size_t)b * NACT + tid] = d;

    float t = (tid < NACT) ? d * logf(fmaxf(d, 1e-20f)) : 0.0f;
    #pragma unroll
    for (int off = 32; off; off >>= 1) t += __shfl_xor(t, off);
    if (lane == 0) red3[wave] = t;
    __syncthreads();
    if (tid == 0)
        ent_out[b] = -(((red3[0] + red3[1]) + (red3[2] + red3[3]))
                     + ((red3[4] + red3[5]) + (red3[6] + red3[7])));
}

extern "C" void kernel_launch(void* const* d_in, const int* in_sizes, int n_in,
                              void* d_out, int out_size, void* d_ws, size_t ws_size,
                              hipStream_t stream) {
    const int*   e       = (const int*)d_in[0];
    const int*   q       = (const int*)d_in[1];
    const float* hstate  = (const float*)d_in[2];
    const int*   r_space = (const int*)d_in[3];
    const int*   e_space = (const int*)d_in[4];
    const float* amask   = (const float*)d_in[5];
    const float* ent     = (const float*)d_in[6];
    const float* rel     = (const float*)d_in[7];
    const float* W1      = (const float*)d_in[8];
    const float* b1      = (const float*)d_in[9];
    const float* W2      = (const float*)d_in[10];
    const float* b2      = (const float*)d_in[11];

    ushort* W1T    = (ushort*)d_ws;                      // 512*1024
    ushort* Bcat   = W1T    + (size_t)ADIM * KTOT;       // 704*512
    ushort* W2low  = Bcat   + (size_t)NCAT * ADIM;       // 512*256
    ushort* relbf  = W2low  + (size_t)ADIM * DIM;        // 400*256
    float*  cvec   = (float*)(relbf + (size_t)NR * DIM); // 448
    float*  Hpart  = cvec   + NRP;                       // 4*1024*512
    ushort* Xbf    = (ushort*)(Hpart + (size_t)4 * NB * ADIM); // 1024*512
    float*  X2upP  = (float*)(Xbf + (size_t)NB * ADIM);  // 2*1024*256
    float*  RtabP  = X2upP  + (size_t)2 * NB * DIM;      // 2*1024*448
    float*  dist   = (float*)d_out;
    float*  entr   = dist + (size_t)NB * NACT;

    prep_kernel<<<390, 256, 0, stream>>>(W1, W2, rel, b2, W1T, Bcat, W2low, relbf, cvec);
    mega2_kernel<<<568, 256, 0, stream>>>(ent, rel, hstate, e, q, W1T, relbf, W2low, Bcat, Hpart);
    reduce_x<<<512, 256, 0, stream>>>(Hpart, b1, Xbf);
    gemm2big<<<dim3(11, 16, 2), 256, 0, stream>>>(Xbf, Bcat, b2, cvec, X2upP, RtabP);
    scores_kernel<<<NB, 512, 0, stream>>>(
        r_space, e_space, amask, ent, RtabP, X2upP, dist, entr);
}

// Round 5
// 218.428 us; speedup vs baseline: 1.0470x; 1.0078x over previous
//
#include <hip/hip_runtime.h>
#include <math.h>

#define NB   1024
#define NACT 256
#define DIM  256
#define HDIM 512
#define ADIM 512
#define KTOT 1024
#define NE   100000
#define NR   400
#define NRP  448
#define NCAT 704            // 256 (X2 upper half) + 448 (Mtab rows)

typedef __attribute__((ext_vector_type(8))) short bf16x8;
typedef __attribute__((ext_vector_type(4))) float f32x4;

__device__ __forceinline__ unsigned short f2bf(float f) {
    unsigned int u = __float_as_uint(f);
    u += 0x7FFF + ((u >> 16) & 1);
    return (unsigned short)(u >> 16);
}
__device__ __forceinline__ ushort4 cvt4(float4 v) {
    ushort4 o = {f2bf(v.x), f2bf(v.y), f2bf(v.z), f2bf(v.w)};
    return o;
}

// ---------------- prep: W1T, Bcat[0:256)=W2T_upper, W2lowbf, relbf, cvec ----------------
__global__ __launch_bounds__(256) void prep_kernel(
    const float* __restrict__ W1, const float* __restrict__ W2,
    const float* __restrict__ rel, const float* __restrict__ b2,
    ushort* __restrict__ W1T, ushort* __restrict__ Bcat,
    ushort* __restrict__ W2lowbf, ushort* __restrict__ relbf,
    float* __restrict__ cvec)
{
    const int blk = blockIdx.x, tid = threadIdx.x;
    if (blk < 160) {
        // transpose fp32 [K][512] -> bf16 [n][K]
        __shared__ float t[64][68];
        const float* in; ushort* out; int Kd, k0, n0, rowbase;
        if (blk < 128) {                  // W1: K=1024, 16 k-tiles x 8 n-tiles
            in = W1; out = W1T; Kd = 1024;
            k0 = (blk >> 3) * 64; n0 = (blk & 7) * 64; rowbase = n0;
        } else {                          // W2 upper: K=512, 8 k-tiles x 4 n-tiles
            const int l = blk - 128;
            in = W2; out = Bcat; Kd = 512;
            k0 = (l >> 2) * 64; n0 = 256 + (l & 3) * 64; rowbase = n0 - 256;
        }
        const int kr = tid >> 2, c = tid & 3;
        #pragma unroll
        for (int j = 0; j < 4; ++j) {
            const float4 v = *(const float4*)(in + (size_t)(k0 + kr) * ADIM + n0 + c * 16 + j * 4);
            *(float4*)&t[kr][c * 16 + j * 4] = v;
        }
        __syncthreads();
        const int nr = tid >> 2;
        ushort tmp[16];
        #pragma unroll
        for (int kk = 0; kk < 16; ++kk) tmp[kk] = f2bf(t[c * 16 + kk][nr]);
        *(uint4*)(out + (size_t)(rowbase + nr) * Kd + k0 + c * 16)     = *(uint4*)&tmp[0];
        *(uint4*)(out + (size_t)(rowbase + nr) * Kd + k0 + c * 16 + 8) = *(uint4*)&tmp[8];
    } else if (blk < 288) {
        // W2lowbf[k][d] = bf16(W2[k][d]), d<256 ; 4 rows per block
        const int l = blk - 160;
        const int row = l * 4 + (tid >> 6);
        const int d4  = tid & 63;
        const float4 v = *(const float4*)(W2 + (size_t)row * ADIM + d4 * 4);
        *(ushort4*)(W2lowbf + (size_t)row * DIM + d4 * 4) = cvt4(v);
    } else if (blk < 388) {
        const int j = (blk - 288) * 256 + tid;     // 25600 float4
        ((ushort4*)relbf)[j] = cvt4(((const float4*)rel)[j]);
    } else {
        const int r = (blk - 388) * 256 + tid;
        if (r < NRP) {
            const int rr = (r < NR) ? r : (NR - 1);
            const float* a = rel + (size_t)rr * DIM;
            float s = 0.f;
            for (int d = 0; d < DIM; d += 4) {
                const float4 av = *(const float4*)(a + d);
                const float4 bv = *(const float4*)(b2 + d);
                s += av.x * bv.x + av.y * bv.y + av.z * bv.z + av.w * bv.w;
            }
            cvec[r] = s;
        }
    }
}

// ---------------- mega2: [0,56) gemm_M ; [56,568) gemm1 split-K=4 ----------------
__global__ __launch_bounds__(256) void mega2_kernel(
    const float* __restrict__ ent, const float* __restrict__ rel,
    const float* __restrict__ hstate,
    const int* __restrict__ e, const int* __restrict__ q,
    const ushort* __restrict__ W1T, const ushort* __restrict__ relbf,
    const ushort* __restrict__ W2lowbf,
    ushort* __restrict__ Bcat, float* __restrict__ Hpart)
{
    __shared__ __align__(16) ushort Als[64][40];
    __shared__ __align__(16) ushort Bls[64][40];
    const int blk = blockIdx.x, tid = threadIdx.x;
    const int wave = tid >> 6, lane = tid & 63;
    const int qq   = lane >> 4, l15 = lane & 15;
    const int sm   = tid >> 2, sc = tid & 3;

    f32x4 acc[4];
    #pragma unroll
    for (int mt = 0; mt < 4; ++mt) acc[mt] = (f32x4){0.f, 0.f, 0.f, 0.f};

    if (blk < 56) {
        // ---- gemm_M: Mtab[r][k] = relbf[r,:] . W2lowbf[k,:]  -> Bcat rows 256+r ----
        const int n0 = (blk & 7) * 64;            // k-dim tile
        const int m0 = (blk >> 3) * 64;           // r tile (0..384)
        const int arow = (m0 + sm < NR) ? (m0 + sm) : (NR - 1);
        const uint4* ga = (const uint4*)(relbf + (size_t)arow * DIM) + sc;
        const uint4* gb = (const uint4*)(W2lowbf + (size_t)(n0 + sm) * DIM) + sc;
        uint4 pa = ga[0], pb = gb[0];
        for (int it = 0; it < DIM / 32; ++it) {
            *(uint4*)&Als[sm][sc * 8] = pa;
            *(uint4*)&Bls[sm][sc * 8] = pb;
            __syncthreads();
            if (it + 1 < DIM / 32) { pa = ga[(it + 1) * 4]; pb = gb[(it + 1) * 4]; }
            const bf16x8 bfrag = *(const bf16x8*)&Bls[wave * 16 + l15][qq * 8];
            #pragma unroll
            for (int mt = 0; mt < 4; ++mt) {
                const bf16x8 afrag = *(const bf16x8*)&Als[mt * 16 + l15][qq * 8];
                acc[mt] = __builtin_amdgcn_mfma_f32_16x16x32_bf16(afrag, bfrag, acc[mt], 0, 0, 0);
            }
            __syncthreads();
        }
        const int n = n0 + wave * 16 + l15;
        #pragma unroll
        for (int mt = 0; mt < 4; ++mt)
            #pragma unroll
            for (int r = 0; r < 4; ++r) {
                const int m = m0 + mt * 16 + qq * 4 + r;
                Bcat[(size_t)(256 + m) * ADIM + n] = f2bf(acc[mt][r]);
            }
        return;
    }

    // ---- gemm1 split-K: Hpart[z] = gather[E|H|Q]_chunk @ W1T_chunk^T ----
    const int g  = blk - 56;                      // 0..511
    const int n0 = (g & 7) * 64;
    const int m0 = ((g >> 3) & 15) * 64;
    const int z  = g >> 7;                        // 0..3, k-chunks of 256
    const int kbase = z * 256;
    const int kofs  = sc * 8;

    const int row = m0 + sm;
    const float* abase;
    if (z == 0)      abase = ent + (size_t)e[row] * DIM;
    else if (z == 3) abase = rel + (size_t)q[row] * DIM;
    else             abase = hstate + (size_t)row * HDIM + (kbase - DIM);
    const uint4* gb = (const uint4*)(W1T + (size_t)(n0 + sm) * KTOT + kbase) + sc;

    float4 pa0 = *(const float4*)(abase + kofs);
    float4 pa1 = *(const float4*)(abase + kofs + 4);
    uint4  pb  = gb[0];

    for (int it = 0; it < 8; ++it) {
        ushort t8[8];
        t8[0] = f2bf(pa0.x); t8[1] = f2bf(pa0.y); t8[2] = f2bf(pa0.z); t8[3] = f2bf(pa0.w);
        t8[4] = f2bf(pa1.x); t8[5] = f2bf(pa1.y); t8[6] = f2bf(pa1.z); t8[7] = f2bf(pa1.w);
        *(uint4*)&Als[sm][sc * 8] = *(uint4*)t8;
        *(uint4*)&Bls[sm][sc * 8] = pb;
        __syncthreads();
        if (it + 1 < 8) {
            const int lofs = (it + 1) * 32 + kofs;
            pa0 = *(const float4*)(abase + lofs);
            pa1 = *(const float4*)(abase + lofs + 4);
            pb  = gb[(it + 1) * 4];
        }
        const bf16x8 bfrag = *(const bf16x8*)&Bls[wave * 16 + l15][qq * 8];
        #pragma unroll
        for (int mt = 0; mt < 4; ++mt) {
            const bf16x8 afrag = *(const bf16x8*)&Als[mt * 16 + l15][qq * 8];
            acc[mt] = __builtin_amdgcn_mfma_f32_16x16x32_bf16(afrag, bfrag, acc[mt], 0, 0, 0);
        }
        __syncthreads();
    }
    float* dst = Hpart + (size_t)z * NB * ADIM;
    const int n = n0 + wave * 16 + l15;
    #pragma unroll
    for (int mt = 0; mt < 4; ++mt)
        #pragma unroll
        for (int r = 0; r < 4; ++r) {
            const int m = m0 + mt * 16 + qq * 4 + r;
            dst[(size_t)m * ADIM + n] = acc[mt][r];
        }
}

// ------- reduce_x: Xbf[m][k] = bf16(relu(sum_z Hpart[z][m][k] + b1[k])) -------
__global__ __launch_bounds__(256) void reduce_x(
    const float* __restrict__ Hpart, const float* __restrict__ b1,
    ushort* __restrict__ Xbf)
{
    const int i = blockIdx.x * 256 + threadIdx.x;     // float4 index, 512 blocks
    const int col4 = i & (ADIM / 4 - 1);
    float4 s = ((const float4*)b1)[col4];
    #pragma unroll
    for (int z = 0; z < 4; ++z) {
        const float4 h = ((const float4*)(Hpart + (size_t)z * NB * ADIM))[i];
        s.x += h.x; s.y += h.y; s.z += h.z; s.w += h.w;
    }
    s.x = fmaxf(s.x, 0.f); s.y = fmaxf(s.y, 0.f);
    s.z = fmaxf(s.z, 0.f); s.w = fmaxf(s.w, 0.f);
    ((ushort4*)Xbf)[i] = cvt4(s);
}

// ------- gemm2big split-K=2: [X2up | Rtab]_part[z] = Xbf_chunk @ Bcat_chunk^T -------
__global__ __launch_bounds__(256) void gemm2big(
    const ushort* __restrict__ Xbf, const ushort* __restrict__ Bcat,
    const float* __restrict__ b2, const float* __restrict__ cvec,
    float* __restrict__ X2upPart, float* __restrict__ RtabPart)
{
    __shared__ __align__(16) ushort Als[64][40];
    __shared__ __align__(16) ushort Bls[64][40];
    const int tid  = threadIdx.x;
    const int n0   = blockIdx.x * 64;             // 0..640
    const int m0   = blockIdx.y * 64;
    const int z    = blockIdx.z;                  // 0,1 ; k-chunk of 256
    const int kb   = z * 256;
    const int wave = tid >> 6, lane = tid & 63;
    const int qq   = lane >> 4, l15 = lane & 15;
    const int sm   = tid >> 2, sc = tid & 3;

    const uint4* gap = (const uint4*)(Xbf  + (size_t)(m0 + sm) * ADIM + kb) + sc;
    const uint4* gbp = (const uint4*)(Bcat + (size_t)(n0 + sm) * ADIM + kb) + sc;

    f32x4 acc[4];
    #pragma unroll
    for (int mt = 0; mt < 4; ++mt) acc[mt] = (f32x4){0.f, 0.f, 0.f, 0.f};

    uint4 pa = gap[0], pb = gbp[0];
    for (int it = 0; it < 8; ++it) {
        *(uint4*)&Als[sm][sc * 8] = pa;
        *(uint4*)&Bls[sm][sc * 8] = pb;
        __syncthreads();
        if (it + 1 < 8) { pa = gap[(it + 1) * 4]; pb = gbp[(it + 1) * 4]; }
        const bf16x8 bfrag = *(const bf16x8*)&Bls[wave * 16 + l15][qq * 8];
        #pragma unroll
        for (int mt = 0; mt < 4; ++mt) {
            const bf16x8 afrag = *(const bf16x8*)&Als[mt * 16 + l15][qq * 8];
            acc[mt] = __builtin_amdgcn_mfma_f32_16x16x32_bf16(afrag, bfrag, acc[mt], 0, 0, 0);
        }
        __syncthreads();
    }
    const int n = n0 + wave * 16 + l15;
    const float extra = (z == 0) ? ((n < 256) ? b2[256 + n] : cvec[n - 256]) : 0.0f;
    #pragma unroll
    for (int mt = 0; mt < 4; ++mt)
        #pragma unroll
        for (int r = 0; r < 4; ++r) {
            const int m = m0 + mt * 16 + qq * 4 + r;
            const float v = acc[mt][r] + extra;
            if (n < 256) X2upPart[(size_t)z * NB * DIM + (size_t)m * DIM + n] = v;
            else         RtabPart[(size_t)z * NB * NRP + (size_t)m * NRP + (n - 256)] = v;
        }
}

// ------- scores: full-wave coalesced row loads (16 lines/instr), 8 actions in flight -------
__global__ __launch_bounds__(512, 8) void scores_kernel(
    const int* __restrict__ r_space, const int* __restrict__ e_space,
    const float* __restrict__ amask,
    const float* __restrict__ ent,
    const float* __restrict__ RtabPart, const float* __restrict__ X2upPart,
    float* __restrict__ dist_out, float* __restrict__ ent_out)
{
    const int b    = blockIdx.x;
    const int tid  = threadIdx.x;
    const int wave = tid >> 6;
    const int lane = tid & 63;

    __shared__ float xs[DIM];
    __shared__ float rtab[NRP];
    __shared__ float sc[NACT];
    __shared__ int   eidx[NACT];
    __shared__ int   ridx[NACT];
    __shared__ float red1[8], red2[8], red3[8];

    // stage: indices (coalesced), rtab = R0+R1, xs = X0+X1
    if (tid < NACT) eidx[tid] = e_space[(size_t)b * NACT + tid];
    else            ridx[tid - NACT] = r_space[(size_t)b * NACT + tid - NACT];
    if (tid < 112) {
        const float4 v0 = ((const float4*)(RtabPart + (size_t)b * NRP))[tid];
        const float4 v1 = ((const float4*)(RtabPart + (size_t)NB * NRP + (size_t)b * NRP))[tid];
        float4 s; s.x = v0.x + v1.x; s.y = v0.y + v1.y; s.z = v0.z + v1.z; s.w = v0.w + v1.w;
        ((float4*)rtab)[tid] = s;
    } else if (tid >= 128 && tid < 192) {
        const int j = tid - 128;
        float4 v0 = ((const float4*)(X2upPart + (size_t)b * DIM))[j];
        const float4 v1 = ((const float4*)(X2upPart + (size_t)NB * DIM + (size_t)b * DIM))[j];
        v0.x += v1.x; v0.y += v1.y; v0.z += v1.z; v0.w += v1.w;
        ((float4*)xs)[j] = v0;
    }
    __syncthreads();

    // this lane's x chunk: dims [4*lane, 4*lane+4) -> one float4 in regs
    const float4 x = ((const float4*)xs)[lane];

    // wave w owns actions [w*32, w*32+32), processed in 4 chunks of 8.
    // each load instruction is fully wave-coalesced: one 1KB row, lane i -> bytes [16i,16i+16)
    const int abase0 = wave * 32;
    #pragma unroll
    for (int c = 0; c < 4; ++c) {
        const int ab = abase0 + c * 8;
        float4 ev[8];
        #pragma unroll
        for (int j = 0; j < 8; ++j)
            ev[j] = ((const float4*)(ent + (size_t)eidx[ab + j] * DIM))[lane];
        float p[8];
        #pragma unroll
        for (int j = 0; j < 8; ++j)
            p[j] = ev[j].x * x.x + ev[j].y * x.y + ev[j].z * x.z + ev[j].w * x.w;
        #pragma unroll
        for (int off = 32; off; off >>= 1) {
            #pragma unroll
            for (int j = 0; j < 8; ++j) p[j] += __shfl_xor(p[j], off);
        }
        // lane j (0..7) writes action ab+j
        float out = p[0];
        #pragma unroll
        for (int j = 1; j < 8; ++j) out = (lane == j) ? p[j] : out;
        if (lane < 8) {
            const int a = ab + lane;
            sc[a] = out + rtab[ridx[a]];
        }
    }
    __syncthreads();

    // masked softmax + entropy over 256 actions (512 threads, top half contributes identity)
    float s = -3.0e38f;
    if (tid < NACT) {
        const float m = amask[(size_t)b * NACT + tid];
        s = sc[tid] - (1.0f - m) * 1e31f;
    }

    float mx = s;
    #pragma unroll
    for (int off = 32; off; off >>= 1) mx = fmaxf(mx, __shfl_xor(mx, off));
    if (lane == 0) red1[wave] = mx;
    __syncthreads();
    mx = fmaxf(fmaxf(fmaxf(red1[0], red1[1]), fmaxf(red1[2], red1[3])),
               fmaxf(fmaxf(red1[4], red1[5]), fmaxf(red1[6], red1[7])));

    const float ex = (tid < NACT) ? expf(s - mx) : 0.0f;
    float sum = ex;
    #pragma unroll
    for (int off = 32; off; off >>= 1) sum += __shfl_xor(sum, off);
    if (lane == 0) red2[wave] = sum;
    __syncthreads();
    sum = ((red2[0] + red2[1]) + (red2[2] + red2[3]))
        + ((red2[4] + red2[5]) + (red2[6] + red2[7]));

    const float d = ex / sum;
    if (tid < NACT) dist_out[(size_t)b * NACT + tid] = d;

    float t = (tid < NACT) ? d * logf(fmaxf(d, 1e-20f)) : 0.0f;
    #pragma unroll
    for (int off = 32; off; off >>= 1) t += __shfl_xor(t, off);
    if (lane == 0) red3[wave] = t;
    __syncthreads();
    if (tid == 0)
        ent_out[b] = -(((red3[0] + red3[1]) + (red3[2] + red3[3]))
                     + ((red3[4] + red3[5]) + (red3[6] + red3[7])));
}

extern "C" void kernel_launch(void* const* d_in, const int* in_sizes, int n_in,
                              void* d_out, int out_size, void* d_ws, size_t ws_size,
                              hipStream_t stream) {
    const int*   e       = (const int*)d_in[0];
    const int*   q       = (const int*)d_in[1];
    const float* hstate  = (const float*)d_in[2];
    const int*   r_space = (const int*)d_in[3];
    const int*   e_space = (const int*)d_in[4];
    const float* amask   = (const float*)d_in[5];
    const float* ent     = (const float*)d_in[6];
    const float* rel     = (const float*)d_in[7];
    const float* W1      = (const float*)d_in[8];
    const float* b1      = (const float*)d_in[9];
    const float* W2      = (const float*)d_in[10];
    const float* b2      = (const float*)d_in[11];

    ushort* W1T    = (ushort*)d_ws;                      // 512*1024
    ushort* Bcat   = W1T    + (size_t)ADIM * KTOT;       // 704*512
    ushort* W2low  = Bcat   + (size_t)NCAT * ADIM;       // 512*256
    ushort* relbf  = W2low  + (size_t)ADIM * DIM;        // 400*256
    float*  cvec   = (float*)(relbf + (size_t)NR * DIM); // 448
    float*  Hpart  = cvec   + NRP;                       // 4*1024*512
    ushort* Xbf    = (ushort*)(Hpart + (size_t)4 * NB * ADIM); // 1024*512
    float*  X2upP  = (float*)(Xbf + (size_t)NB * ADIM);  // 2*1024*256
    float*  RtabP  = X2upP  + (size_t)2 * NB * DIM;      // 2*1024*448
    float*  dist   = (float*)d_out;
    float*  entr   = dist + (size_t)NB * NACT;

    prep_kernel<<<390, 256, 0, stream>>>(W1, W2, rel, b2, W1T, Bcat, W2low, relbf, cvec);
    mega2_kernel<<<568, 256, 0, stream>>>(ent, rel, hstate, e, q, W1T, relbf, W2low, Bcat, Hpart);
    reduce_x<<<512, 256, 0, stream>>>(Hpart, b1, Xbf);
    gemm2big<<<dim3(11, 16, 2), 256, 0, stream>>>(Xbf, Bcat, b2, cvec, X2upP, RtabP);
    scores_kernel<<<NB, 512, 0, stream>>>(
        r_space, e_space, amask, ent, RtabP, X2upP, dist, entr);
}

// Round 6
// 212.145 us; speedup vs baseline: 1.0780x; 1.0296x over previous
//
#include <hip/hip_runtime.h>
#include <math.h>

#define NB   1024
#define NACT 256
#define DIM  256
#define HDIM 512
#define ADIM 512
#define KTOT 1024
#define NE   100000
#define NR   400
#define NRP  448
#define NCAT 704            // 256 (X2 upper half) + 448 (Mtab rows)

typedef __attribute__((ext_vector_type(8))) short bf16x8;
typedef __attribute__((ext_vector_type(4))) float f32x4;

__device__ __forceinline__ unsigned short f2bf(float f) {
    unsigned int u = __float_as_uint(f);
    u += 0x7FFF + ((u >> 16) & 1);
    return (unsigned short)(u >> 16);
}
__device__ __forceinline__ ushort4 cvt4(float4 v) {
    ushort4 o = {f2bf(v.x), f2bf(v.y), f2bf(v.z), f2bf(v.w)};
    return o;
}
__device__ __forceinline__ float bf2f(unsigned short u) {
    return __uint_as_float(((unsigned int)u) << 16);
}

// ---------------- prep: W1T, Bcat upper, W2lowbf, relbf, cvec, entbf ----------------
// [0,128): W1T transpose; [128,160): W2T upper -> Bcat; [160,288): W2lowbf;
// [288,388): relbf; [388,390): cvec; [390,3515): entbf = bf16(ent) streaming convert
__global__ __launch_bounds__(256) void prep_kernel(
    const float* __restrict__ W1, const float* __restrict__ W2,
    const float* __restrict__ rel, const float* __restrict__ b2,
    const float* __restrict__ ent,
    ushort* __restrict__ W1T, ushort* __restrict__ Bcat,
    ushort* __restrict__ W2lowbf, ushort* __restrict__ relbf,
    float* __restrict__ cvec, ushort* __restrict__ entbf)
{
    const int blk = blockIdx.x, tid = threadIdx.x;
    if (blk >= 390) {
        // entbf: 25.6M elems = 3.2M float4; 3125 blocks x 1024 float4
        const int base = (blk - 390) * 1024;
        #pragma unroll
        for (int k = 0; k < 4; ++k) {
            const int j = base + k * 256 + tid;
            ((ushort4*)entbf)[j] = cvt4(((const float4*)ent)[j]);
        }
        return;
    }
    if (blk < 160) {
        // transpose fp32 [K][512] -> bf16 [n][K]
        __shared__ float t[64][68];
        const float* in; ushort* out; int Kd, k0, n0, rowbase;
        if (blk < 128) {                  // W1: K=1024, 16 k-tiles x 8 n-tiles
            in = W1; out = W1T; Kd = 1024;
            k0 = (blk >> 3) * 64; n0 = (blk & 7) * 64; rowbase = n0;
        } else {                          // W2 upper: K=512, 8 k-tiles x 4 n-tiles
            const int l = blk - 128;
            in = W2; out = Bcat; Kd = 512;
            k0 = (l >> 2) * 64; n0 = 256 + (l & 3) * 64; rowbase = n0 - 256;
        }
        const int kr = tid >> 2, c = tid & 3;
        #pragma unroll
        for (int j = 0; j < 4; ++j) {
            const float4 v = *(const float4*)(in + (size_t)(k0 + kr) * ADIM + n0 + c * 16 + j * 4);
            *(float4*)&t[kr][c * 16 + j * 4] = v;
        }
        __syncthreads();
        const int nr = tid >> 2;
        ushort tmp[16];
        #pragma unroll
        for (int kk = 0; kk < 16; ++kk) tmp[kk] = f2bf(t[c * 16 + kk][nr]);
        *(uint4*)(out + (size_t)(rowbase + nr) * Kd + k0 + c * 16)     = *(uint4*)&tmp[0];
        *(uint4*)(out + (size_t)(rowbase + nr) * Kd + k0 + c * 16 + 8) = *(uint4*)&tmp[8];
    } else if (blk < 288) {
        // W2lowbf[k][d] = bf16(W2[k][d]), d<256 ; 4 rows per block
        const int l = blk - 160;
        const int row = l * 4 + (tid >> 6);
        const int d4  = tid & 63;
        const float4 v = *(const float4*)(W2 + (size_t)row * ADIM + d4 * 4);
        *(ushort4*)(W2lowbf + (size_t)row * DIM + d4 * 4) = cvt4(v);
    } else if (blk < 388) {
        const int j = (blk - 288) * 256 + tid;     // 25600 float4
        ((ushort4*)relbf)[j] = cvt4(((const float4*)rel)[j]);
    } else {
        const int r = (blk - 388) * 256 + tid;
        if (r < NRP) {
            const int rr = (r < NR) ? r : (NR - 1);
            const float* a = rel + (size_t)rr * DIM;
            float s = 0.f;
            for (int d = 0; d < DIM; d += 4) {
                const float4 av = *(const float4*)(a + d);
                const float4 bv = *(const float4*)(b2 + d);
                s += av.x * bv.x + av.y * bv.y + av.z * bv.z + av.w * bv.w;
            }
            cvec[r] = s;
        }
    }
}

// ---------------- mega2: [0,56) gemm_M ; [56,568) gemm1 split-K=4 ----------------
__global__ __launch_bounds__(256) void mega2_kernel(
    const float* __restrict__ ent, const float* __restrict__ rel,
    const float* __restrict__ hstate,
    const int* __restrict__ e, const int* __restrict__ q,
    const ushort* __restrict__ W1T, const ushort* __restrict__ relbf,
    const ushort* __restrict__ W2lowbf,
    ushort* __restrict__ Bcat, float* __restrict__ Hpart)
{
    __shared__ __align__(16) ushort Als[64][40];
    __shared__ __align__(16) ushort Bls[64][40];
    const int blk = blockIdx.x, tid = threadIdx.x;
    const int wave = tid >> 6, lane = tid & 63;
    const int qq   = lane >> 4, l15 = lane & 15;
    const int sm   = tid >> 2, sc = tid & 3;

    f32x4 acc[4];
    #pragma unroll
    for (int mt = 0; mt < 4; ++mt) acc[mt] = (f32x4){0.f, 0.f, 0.f, 0.f};

    if (blk < 56) {
        // ---- gemm_M: Mtab[r][k] = relbf[r,:] . W2lowbf[k,:]  -> Bcat rows 256+r ----
        const int n0 = (blk & 7) * 64;            // k-dim tile
        const int m0 = (blk >> 3) * 64;           // r tile (0..384)
        const int arow = (m0 + sm < NR) ? (m0 + sm) : (NR - 1);
        const uint4* ga = (const uint4*)(relbf + (size_t)arow * DIM) + sc;
        const uint4* gb = (const uint4*)(W2lowbf + (size_t)(n0 + sm) * DIM) + sc;
        uint4 pa = ga[0], pb = gb[0];
        for (int it = 0; it < DIM / 32; ++it) {
            *(uint4*)&Als[sm][sc * 8] = pa;
            *(uint4*)&Bls[sm][sc * 8] = pb;
            __syncthreads();
            if (it + 1 < DIM / 32) { pa = ga[(it + 1) * 4]; pb = gb[(it + 1) * 4]; }
            const bf16x8 bfrag = *(const bf16x8*)&Bls[wave * 16 + l15][qq * 8];
            #pragma unroll
            for (int mt = 0; mt < 4; ++mt) {
                const bf16x8 afrag = *(const bf16x8*)&Als[mt * 16 + l15][qq * 8];
                acc[mt] = __builtin_amdgcn_mfma_f32_16x16x32_bf16(afrag, bfrag, acc[mt], 0, 0, 0);
            }
            __syncthreads();
        }
        const int n = n0 + wave * 16 + l15;
        #pragma unroll
        for (int mt = 0; mt < 4; ++mt)
            #pragma unroll
            for (int r = 0; r < 4; ++r) {
                const int m = m0 + mt * 16 + qq * 4 + r;
                Bcat[(size_t)(256 + m) * ADIM + n] = f2bf(acc[mt][r]);
            }
        return;
    }

    // ---- gemm1 split-K: Hpart[z] = gather[E|H|Q]_chunk @ W1T_chunk^T ----
    const int g  = blk - 56;                      // 0..511
    const int n0 = (g & 7) * 64;
    const int m0 = ((g >> 3) & 15) * 64;
    const int z  = g >> 7;                        // 0..3, k-chunks of 256
    const int kbase = z * 256;
    const int kofs  = sc * 8;

    const int row = m0 + sm;
    const float* abase;
    if (z == 0)      abase = ent + (size_t)e[row] * DIM;
    else if (z == 3) abase = rel + (size_t)q[row] * DIM;
    else             abase = hstate + (size_t)row * HDIM + (kbase - DIM);
    const uint4* gb = (const uint4*)(W1T + (size_t)(n0 + sm) * KTOT + kbase) + sc;

    float4 pa0 = *(const float4*)(abase + kofs);
    float4 pa1 = *(const float4*)(abase + kofs + 4);
    uint4  pb  = gb[0];

    for (int it = 0; it < 8; ++it) {
        ushort t8[8];
        t8[0] = f2bf(pa0.x); t8[1] = f2bf(pa0.y); t8[2] = f2bf(pa0.z); t8[3] = f2bf(pa0.w);
        t8[4] = f2bf(pa1.x); t8[5] = f2bf(pa1.y); t8[6] = f2bf(pa1.z); t8[7] = f2bf(pa1.w);
        *(uint4*)&Als[sm][sc * 8] = *(uint4*)t8;
        *(uint4*)&Bls[sm][sc * 8] = pb;
        __syncthreads();
        if (it + 1 < 8) {
            const int lofs = (it + 1) * 32 + kofs;
            pa0 = *(const float4*)(abase + lofs);
            pa1 = *(const float4*)(abase + lofs + 4);
            pb  = gb[(it + 1) * 4];
        }
        const bf16x8 bfrag = *(const bf16x8*)&Bls[wave * 16 + l15][qq * 8];
        #pragma unroll
        for (int mt = 0; mt < 4; ++mt) {
            const bf16x8 afrag = *(const bf16x8*)&Als[mt * 16 + l15][qq * 8];
            acc[mt] = __builtin_amdgcn_mfma_f32_16x16x32_bf16(afrag, bfrag, acc[mt], 0, 0, 0);
        }
        __syncthreads();
    }
    float* dst = Hpart + (size_t)z * NB * ADIM;
    const int n = n0 + wave * 16 + l15;
    #pragma unroll
    for (int mt = 0; mt < 4; ++mt)
        #pragma unroll
        for (int r = 0; r < 4; ++r) {
            const int m = m0 + mt * 16 + qq * 4 + r;
            dst[(size_t)m * ADIM + n] = acc[mt][r];
        }
}

// ------- reduce_x: Xbf[m][k] = bf16(relu(sum_z Hpart[z][m][k] + b1[k])) -------
__global__ __launch_bounds__(256) void reduce_x(
    const float* __restrict__ Hpart, const float* __restrict__ b1,
    ushort* __restrict__ Xbf)
{
    const int i = blockIdx.x * 256 + threadIdx.x;     // float4 index, 512 blocks
    const int col4 = i & (ADIM / 4 - 1);
    float4 s = ((const float4*)b1)[col4];
    #pragma unroll
    for (int z = 0; z < 4; ++z) {
        const float4 h = ((const float4*)(Hpart + (size_t)z * NB * ADIM))[i];
        s.x += h.x; s.y += h.y; s.z += h.z; s.w += h.w;
    }
    s.x = fmaxf(s.x, 0.f); s.y = fmaxf(s.y, 0.f);
    s.z = fmaxf(s.z, 0.f); s.w = fmaxf(s.w, 0.f);
    ((ushort4*)Xbf)[i] = cvt4(s);
}

// ------- gemm2big split-K=2: [X2up | Rtab]_part[z] = Xbf_chunk @ Bcat_chunk^T -------
__global__ __launch_bounds__(256) void gemm2big(
    const ushort* __restrict__ Xbf, const ushort* __restrict__ Bcat,
    const float* __restrict__ b2, const float* __restrict__ cvec,
    float* __restrict__ X2upPart, float* __restrict__ RtabPart)
{
    __shared__ __align__(16) ushort Als[64][40];
    __shared__ __align__(16) ushort Bls[64][40];
    const int tid  = threadIdx.x;
    const int n0   = blockIdx.x * 64;             // 0..640
    const int m0   = blockIdx.y * 64;
    const int z    = blockIdx.z;                  // 0,1 ; k-chunk of 256
    const int kb   = z * 256;
    const int wave = tid >> 6, lane = tid & 63;
    const int qq   = lane >> 4, l15 = lane & 15;
    const int sm   = tid >> 2, sc = tid & 3;

    const uint4* gap = (const uint4*)(Xbf  + (size_t)(m0 + sm) * ADIM + kb) + sc;
    const uint4* gbp = (const uint4*)(Bcat + (size_t)(n0 + sm) * ADIM + kb) + sc;

    f32x4 acc[4];
    #pragma unroll
    for (int mt = 0; mt < 4; ++mt) acc[mt] = (f32x4){0.f, 0.f, 0.f, 0.f};

    uint4 pa = gap[0], pb = gbp[0];
    for (int it = 0; it < 8; ++it) {
        *(uint4*)&Als[sm][sc * 8] = pa;
        *(uint4*)&Bls[sm][sc * 8] = pb;
        __syncthreads();
        if (it + 1 < 8) { pa = gap[(it + 1) * 4]; pb = gbp[(it + 1) * 4]; }
        const bf16x8 bfrag = *(const bf16x8*)&Bls[wave * 16 + l15][qq * 8];
        #pragma unroll
        for (int mt = 0; mt < 4; ++mt) {
            const bf16x8 afrag = *(const bf16x8*)&Als[mt * 16 + l15][qq * 8];
            acc[mt] = __builtin_amdgcn_mfma_f32_16x16x32_bf16(afrag, bfrag, acc[mt], 0, 0, 0);
        }
        __syncthreads();
    }
    const int n = n0 + wave * 16 + l15;
    const float extra = (z == 0) ? ((n < 256) ? b2[256 + n] : cvec[n - 256]) : 0.0f;
    #pragma unroll
    for (int mt = 0; mt < 4; ++mt)
        #pragma unroll
        for (int r = 0; r < 4; ++r) {
            const int m = m0 + mt * 16 + qq * 4 + r;
            const float v = acc[mt][r] + extra;
            if (n < 256) X2upPart[(size_t)z * NB * DIM + (size_t)m * DIM + n] = v;
            else         RtabPart[(size_t)z * NB * NRP + (size_t)m * NRP + (n - 256)] = v;
        }
}

// ------- scores: bf16-row gather (8 lines/row, L3-resident), full-wave loads -------
__global__ __launch_bounds__(512) void scores_kernel(
    const int* __restrict__ r_space, const int* __restrict__ e_space,
    const float* __restrict__ amask,
    const ushort* __restrict__ entbf,
    const float* __restrict__ RtabPart, const float* __restrict__ X2upPart,
    float* __restrict__ dist_out, float* __restrict__ ent_out)
{
    const int b    = blockIdx.x;
    const int tid  = threadIdx.x;
    const int wave = tid >> 6;
    const int lane = tid & 63;

    __shared__ float xs[DIM];
    __shared__ float rtab[NRP];
    __shared__ float sc[NACT];
    __shared__ int   eidx[NACT];
    __shared__ int   ridx[NACT];
    __shared__ float red1[8], red2[8], red3[8];

    // stage: indices (coalesced), rtab = R0+R1, xs = X0+X1
    if (tid < NACT) eidx[tid] = e_space[(size_t)b * NACT + tid];
    else            ridx[tid - NACT] = r_space[(size_t)b * NACT + tid - NACT];
    if (tid < 112) {
        const float4 v0 = ((const float4*)(RtabPart + (size_t)b * NRP))[tid];
        const float4 v1 = ((const float4*)(RtabPart + (size_t)NB * NRP + (size_t)b * NRP))[tid];
        float4 s; s.x = v0.x + v1.x; s.y = v0.y + v1.y; s.z = v0.z + v1.z; s.w = v0.w + v1.w;
        ((float4*)rtab)[tid] = s;
    } else if (tid >= 128 && tid < 192) {
        const int j = tid - 128;
        float4 v0 = ((const float4*)(X2upPart + (size_t)b * DIM))[j];
        const float4 v1 = ((const float4*)(X2upPart + (size_t)NB * DIM + (size_t)b * DIM))[j];
        v0.x += v1.x; v0.y += v1.y; v0.z += v1.z; v0.w += v1.w;
        ((float4*)xs)[j] = v0;
    }
    __syncthreads();

    // this lane's x chunk: dims [4*lane, 4*lane+4)
    const float4 x = ((const float4*)xs)[lane];

    // wave w owns actions [w*32, w*32+32), 4 chunks of 8; each load is one
    // fully-coalesced 512B bf16 row: lane i -> bytes [8i, 8i+8)
    const int abase0 = wave * 32;
    #pragma unroll
    for (int c = 0; c < 4; ++c) {
        const int ab = abase0 + c * 8;
        ushort4 ev[8];
        #pragma unroll
        for (int j = 0; j < 8; ++j)
            ev[j] = ((const ushort4*)(entbf + (size_t)eidx[ab + j] * DIM))[lane];
        float p[8];
        #pragma unroll
        for (int j = 0; j < 8; ++j)
            p[j] = bf2f(ev[j].x) * x.x + bf2f(ev[j].y) * x.y
                 + bf2f(ev[j].z) * x.z + bf2f(ev[j].w) * x.w;
        #pragma unroll
        for (int off = 32; off; off >>= 1) {
            #pragma unroll
            for (int j = 0; j < 8; ++j) p[j] += __shfl_xor(p[j], off);
        }
        // lane j (0..7) writes action ab+j
        float out = p[0];
        #pragma unroll
        for (int j = 1; j < 8; ++j) out = (lane == j) ? p[j] : out;
        if (lane < 8) {
            const int a = ab + lane;
            sc[a] = out + rtab[ridx[a]];
        }
    }
    __syncthreads();

    // masked softmax + entropy over 256 actions (512 threads, top half contributes identity)
    float s = -3.0e38f;
    if (tid < NACT) {
        const float m = amask[(size_t)b * NACT + tid];
        s = sc[tid] - (1.0f - m) * 1e31f;
    }

    float mx = s;
    #pragma unroll
    for (int off = 32; off; off >>= 1) mx = fmaxf(mx, __shfl_xor(mx, off));
    if (lane == 0) red1[wave] = mx;
    __syncthreads();
    mx = fmaxf(fmaxf(fmaxf(red1[0], red1[1]), fmaxf(red1[2], red1[3])),
               fmaxf(fmaxf(red1[4], red1[5]), fmaxf(red1[6], red1[7])));

    const float ex = (tid < NACT) ? expf(s - mx) : 0.0f;
    float sum = ex;
    #pragma unroll
    for (int off = 32; off; off >>= 1) sum += __shfl_xor(sum, off);
    if (lane == 0) red2[wave] = sum;
    __syncthreads();
    sum = ((red2[0] + red2[1]) + (red2[2] + red2[3]))
        + ((red2[4] + red2[5]) + (red2[6] + red2[7]));

    const float d = ex / sum;
    if (tid < NACT) dist_out[(size_t)b * NACT + tid] = d;

    float t = (tid < NACT) ? d * logf(fmaxf(d, 1e-20f)) : 0.0f;
    #pragma unroll
    for (int off = 32; off; off >>= 1) t += __shfl_xor(t, off);
    if (lane == 0) red3[wave] = t;
    __syncthreads();
    if (tid == 0)
        ent_out[b] = -(((red3[0] + red3[1]) + (red3[2] + red3[3]))
                     + ((red3[4] + red3[5]) + (red3[6] + red3[7])));
}

extern "C" void kernel_launch(void* const* d_in, const int* in_sizes, int n_in,
                              void* d_out, int out_size, void* d_ws, size_t ws_size,
                              hipStream_t stream) {
    const int*   e       = (const int*)d_in[0];
    const int*   q       = (const int*)d_in[1];
    const float* hstate  = (const float*)d_in[2];
    const int*   r_space = (const int*)d_in[3];
    const int*   e_space = (const int*)d_in[4];
    const float* amask   = (const float*)d_in[5];
    const float* ent     = (const float*)d_in[6];
    const float* rel     = (const float*)d_in[7];
    const float* W1      = (const float*)d_in[8];
    const float* b1      = (const float*)d_in[9];
    const float* W2      = (const float*)d_in[10];
    const float* b2      = (const float*)d_in[11];

    ushort* W1T    = (ushort*)d_ws;                      // 512*1024
    ushort* Bcat   = W1T    + (size_t)ADIM * KTOT;       // 704*512
    ushort* W2low  = Bcat   + (size_t)NCAT * ADIM;       // 512*256
    ushort* relbf  = W2low  + (size_t)ADIM * DIM;        // 400*256
    float*  cvec   = (float*)(relbf + (size_t)NR * DIM); // 448
    float*  Hpart  = cvec   + NRP;                       // 4*1024*512
    ushort* Xbf    = (ushort*)(Hpart + (size_t)4 * NB * ADIM); // 1024*512
    float*  X2upP  = (float*)(Xbf + (size_t)NB * ADIM);  // 2*1024*256
    float*  RtabP  = X2upP  + (size_t)2 * NB * DIM;      // 2*1024*448
    ushort* entbf  = (ushort*)(RtabP + (size_t)2 * NB * NRP); // 100000*256 bf16 (51.2 MB)
    float*  dist   = (float*)d_out;
    float*  entr   = dist + (size_t)NB * NACT;

    prep_kernel<<<3515, 256, 0, stream>>>(W1, W2, rel, b2, ent,
                                          W1T, Bcat, W2low, relbf, cvec, entbf);
    mega2_kernel<<<568, 256, 0, stream>>>(ent, rel, hstate, e, q, W1T, relbf, W2low, Bcat, Hpart);
    reduce_x<<<512, 256, 0, stream>>>(Hpart, b1, Xbf);
    gemm2big<<<dim3(11, 16, 2), 256, 0, stream>>>(Xbf, Bcat, b2, cvec, X2upP, RtabP);
    scores_kernel<<<NB, 512, 0, stream>>>(
        r_space, e_space, amask, entbf, RtabP, X2upP, dist, entr);
}